// Round 1
// baseline (519.104 us; speedup 1.0000x reference)
//
#include <hip/hip_runtime.h>
#include <stdint.h>

#define N_TOK 4096
#define DIM   1024
#define NCLS  32000
#define IGNIDX (-100)
#define BM 128
#define BN 128
#define BK 64
#define NTILE (NCLS / BN)   // 250
#define MBLK  (N_TOK / BM)  // 32

typedef float  f32x4  __attribute__((ext_vector_type(4)));
typedef __bf16 bf16x8 __attribute__((ext_vector_type(8)));
typedef unsigned short u16;
typedef u16 u16x8 __attribute__((ext_vector_type(8)));

__device__ __forceinline__ u16 f2bf(float f) {
  union { float f; uint32_t u; } c; c.f = f;
  uint32_t u = c.u;
  return (u16)((u + 0x7fffu + ((u >> 16) & 1u)) >> 16);  // RNE
}

// ---- fp32 -> bf16 bulk convert, 8 elems/thread ----
__global__ void cvt_bf16(const float4* __restrict__ in, u16x8* __restrict__ out, int n8) {
  int i = blockIdx.x * 256 + threadIdx.x;
  if (i >= n8) return;
  float4 a = in[2 * i], b = in[2 * i + 1];
  u16x8 o;
  o[0] = f2bf(a.x); o[1] = f2bf(a.y); o[2] = f2bf(a.z); o[3] = f2bf(a.w);
  o[4] = f2bf(b.x); o[5] = f2bf(b.y); o[6] = f2bf(b.z); o[7] = f2bf(b.w);
  out[i] = o;
}

// ---- effective targets, ignore flags, divisor ----
__global__ void prep_targ(const int* __restrict__ targ, int* __restrict__ teff,
                          int* __restrict__ ign, float* __restrict__ divisor) {
  __shared__ int cnt[16];
  int local = 0;
  for (int i = threadIdx.x; i < N_TOK; i += 1024) {
    int t = targ[i];
    if (t != IGNIDX) local++;
    int pos = i & (N_TOK / 4 - 1);        // chunk = 1024
    int te;
    if (pos < N_TOK / 4 - 1)      te = targ[i + 1];
    else if (i == N_TOK - 1)      te = IGNIDX;
    else                          te = targ[i + 2];
    ign[i] = (te == IGNIDX) ? 1 : 0;
    te = te < 0 ? 0 : (te > NCLS - 1 ? NCLS - 1 : te);
    teff[i] = te;
  }
#pragma unroll
  for (int d = 1; d < 64; d <<= 1) local += __shfl_xor(local, d);
  if ((threadIdx.x & 63) == 0) cnt[threadIdx.x >> 6] = local;
  __syncthreads();
  if (threadIdx.x == 0) {
    int t = 0;
    for (int i = 0; i < 16; i++) t += cnt[i];
    divisor[0] = (float)t;
  }
}

// ---- fused GEMM tile + online per-tile (max, sumexp) partials ----
__launch_bounds__(256)
__global__ void gemm_lse(const u16* __restrict__ Xb, const u16* __restrict__ Wb,
                         const int* __restrict__ teff, float* __restrict__ gt,
                         float2* __restrict__ partial) {
  __shared__ u16 Al[BM][BK];
  __shared__ u16 Bl[BN][BK];
  __shared__ float red_m[2][BM];
  __shared__ float red_s[2][BM];

  const int tid = threadIdx.x;
  const int w = tid >> 6, l = tid & 63;
  const int rb = blockIdx.x, tn = blockIdx.y;
  const int rowBase = rb * BM, colBase = tn * BN;
  const int wr = w >> 1, wc = w & 1;

  f32x4 acc[4][4] = {};

  const u16* ga = Xb + (size_t)(rowBase + w * 8 + (l >> 3)) * DIM + (l & 7) * 8;
  const u16* gb = Wb + (size_t)(colBase + w * 8 + (l >> 3)) * DIM + (l & 7) * 8;

  for (int k0 = 0; k0 < DIM; k0 += BK) {
#pragma unroll
    for (int i = 0; i < 4; i++) {
      __builtin_amdgcn_global_load_lds(
          (__attribute__((address_space(1))) void*)(ga + (size_t)i * 32 * DIM + k0),
          (__attribute__((address_space(3))) void*)(&Al[i * 32 + w * 8][0]), 16, 0, 0);
      __builtin_amdgcn_global_load_lds(
          (__attribute__((address_space(1))) void*)(gb + (size_t)i * 32 * DIM + k0),
          (__attribute__((address_space(3))) void*)(&Bl[i * 32 + w * 8][0]), 16, 0, 0);
    }
    __syncthreads();
#pragma unroll
    for (int kk = 0; kk < 2; kk++) {
      bf16x8 af[4], bfr[4];
#pragma unroll
      for (int m = 0; m < 4; m++)
        af[m] = *(const bf16x8*)&Al[wr * 64 + m * 16 + (l & 15)][kk * 32 + (l >> 4) * 8];
#pragma unroll
      for (int n = 0; n < 4; n++)
        bfr[n] = *(const bf16x8*)&Bl[wc * 64 + n * 16 + (l & 15)][kk * 32 + (l >> 4) * 8];
#pragma unroll
      for (int m = 0; m < 4; m++)
#pragma unroll
        for (int n = 0; n < 4; n++)
          acc[m][n] = __builtin_amdgcn_mfma_f32_16x16x32_bf16(af[m], bfr[n], acc[m][n], 0, 0, 0);
    }
    __syncthreads();
  }

  // epilogue: per-row tile max & sum(exp), gt extraction
#pragma unroll
  for (int m = 0; m < 4; m++) {
#pragma unroll
    for (int j = 0; j < 4; j++) {
      const int rloc = wr * 64 + m * 16 + (l >> 4) * 4 + j;
      const int gr = rowBase + rloc;
      const int te = teff[gr];
      float vmax = -1e30f;
#pragma unroll
      for (int n = 0; n < 4; n++) {
        float v = acc[m][n][j];
        int gc = colBase + wc * 64 + n * 16 + (l & 15);
        if (te == gc) gt[gr] = v;
        vmax = fmaxf(vmax, v);
      }
#pragma unroll
      for (int d = 1; d < 16; d <<= 1) vmax = fmaxf(vmax, __shfl_xor(vmax, d));
      float s = 0.f;
#pragma unroll
      for (int n = 0; n < 4; n++) s += __expf(acc[m][n][j] - vmax);
#pragma unroll
      for (int d = 1; d < 16; d <<= 1) s += __shfl_xor(s, d);
      if ((l & 15) == 0) {
        red_m[wc][rloc] = vmax;
        red_s[wc][rloc] = s;
      }
    }
  }
  __syncthreads();
  if (tid < BM) {
    float m0 = red_m[0][tid], m1 = red_m[1][tid];
    float s0 = red_s[0][tid], s1 = red_s[1][tid];
    float M = fmaxf(m0, m1);
    float S = s0 * __expf(m0 - M) + s1 * __expf(m1 - M);
    partial[(size_t)(rowBase + tid) * NTILE + tn] = make_float2(M, S);
  }
}

// ---- combine 250 tile partials per row -> per-token loss ----
__global__ void reduce_lse(const float2* __restrict__ partial, const float* __restrict__ gt,
                           const int* __restrict__ ign, const float* __restrict__ divisor,
                           float* __restrict__ pertok) {
  int r = blockIdx.x * 4 + (threadIdx.x >> 6);
  int l = threadIdx.x & 63;
  float M = -1e30f;
  for (int p = l; p < NTILE; p += 64) M = fmaxf(M, partial[(size_t)r * NTILE + p].x);
#pragma unroll
  for (int d = 1; d < 64; d <<= 1) M = fmaxf(M, __shfl_xor(M, d));
  float S = 0.f;
  for (int p = l; p < NTILE; p += 64) {
    float2 v = partial[(size_t)r * NTILE + p];
    S += v.y * __expf(v.x - M);
  }
#pragma unroll
  for (int d = 1; d < 64; d <<= 1) S += __shfl_xor(S, d);
  if (l == 0) {
    float lse = M + __logf(S);
    pertok[r] = ign[r] ? 0.f : (lse - gt[r]) / divisor[0];
  }
}

// ---- deterministic final sum ----
__global__ void final_sum(const float* __restrict__ pertok, float* __restrict__ out) {
  __shared__ float red[16];
  float s = 0.f;
  for (int i = threadIdx.x; i < N_TOK; i += 1024) s += pertok[i];
#pragma unroll
  for (int d = 1; d < 64; d <<= 1) s += __shfl_xor(s, d);
  if ((threadIdx.x & 63) == 0) red[threadIdx.x >> 6] = s;
  __syncthreads();
  if (threadIdx.x == 0) {
    float t = 0.f;
    for (int i = 0; i < 16; i++) t += red[i];
    out[0] = t;
  }
}

extern "C" void kernel_launch(void* const* d_in, const int* in_sizes, int n_in,
                              void* d_out, int out_size, void* d_ws, size_t ws_size,
                              hipStream_t stream) {
  const float* x = (const float*)d_in[0];       // [4096,1024] f32
  const float* w = (const float*)d_in[1];       // [32000,1024] f32
  const int* targ = (const int*)d_in[2];        // [4096] int
  float* out = (float*)d_out;

  char* ws = (char*)d_ws;
  // workspace layout (~78.4 MiB total)
  u16*    Xb      = (u16*)(ws);                         // 8,388,608 B
  u16*    Wb      = (u16*)(ws + 8388608);               // 65,536,000 B
  float2* partial = (float2*)(ws + 73924608);           // 8,192,000 B
  float*  gt      = (float*)(ws + 82116608);            // 16,384 B
  int*    teff    = (int*)(ws + 82132992);              // 16,384 B
  int*    ign     = (int*)(ws + 82149376);              // 16,384 B
  float*  divisor = (float*)(ws + 82165760);            // 256 B
  float*  pertok  = (float*)(ws + 82166016);            // 16,384 B

  {
    int n8 = N_TOK * DIM / 8;                           // 524288
    cvt_bf16<<<(n8 + 255) / 256, 256, 0, stream>>>((const float4*)x, (u16x8*)Xb, n8);
  }
  {
    int n8 = NCLS * DIM / 8;                            // 4,096,000
    cvt_bf16<<<(n8 + 255) / 256, 256, 0, stream>>>((const float4*)w, (u16x8*)Wb, n8);
  }
  prep_targ<<<1, 1024, 0, stream>>>(targ, teff, ign, divisor);

  dim3 grid(MBLK, NTILE);                               // 32 x 250 = 8000 blocks
  gemm_lse<<<grid, 256, 0, stream>>>(Xb, Wb, teff, gt, partial);

  reduce_lse<<<N_TOK / 4, 256, 0, stream>>>(partial, gt, ign, divisor, pertok);
  final_sum<<<1, 1024, 0, stream>>>(pertok, out);
}

// Round 2
// 373.329 us; speedup vs baseline: 1.3905x; 1.3905x over previous
//
#include <hip/hip_runtime.h>
#include <stdint.h>

#define N_TOK 4096
#define DIM   1024
#define NCLS  32000
#define IGNIDX (-100)
#define BM 256
#define BN 256
#define BK 64
#define NTN (NCLS / BN)     // 125 col-tiles
#define NTM (N_TOK / BM)    // 16 row-tiles
#define KT  (DIM / BK)      // 16 K-tiles

typedef float  f32x4  __attribute__((ext_vector_type(4)));
typedef __bf16 bf16x8 __attribute__((ext_vector_type(8)));
typedef unsigned short u16;
typedef u16 u16x8 __attribute__((ext_vector_type(8)));

__device__ __forceinline__ u16 f2bf(float f) {
  union { float f; uint32_t u; } c; c.f = f;
  uint32_t u = c.u;
  return (u16)((u + 0x7fffu + ((u >> 16) & 1u)) >> 16);  // RNE
}

// ---- fp32 -> bf16 bulk convert, 8 elems/thread ----
__global__ void cvt_bf16(const float4* __restrict__ in, u16x8* __restrict__ out, int n8) {
  int i = blockIdx.x * 256 + threadIdx.x;
  if (i >= n8) return;
  float4 a = in[2 * i], b = in[2 * i + 1];
  u16x8 o;
  o[0] = f2bf(a.x); o[1] = f2bf(a.y); o[2] = f2bf(a.z); o[3] = f2bf(a.w);
  o[4] = f2bf(b.x); o[5] = f2bf(b.y); o[6] = f2bf(b.z); o[7] = f2bf(b.w);
  out[i] = o;
}

// ---- effective targets, ignore flags, divisor ----
__global__ void prep_targ(const int* __restrict__ targ, int* __restrict__ teff,
                          int* __restrict__ ign, float* __restrict__ divisor) {
  __shared__ int cnt[16];
  int local = 0;
  for (int i = threadIdx.x; i < N_TOK; i += 1024) {
    int t = targ[i];
    if (t != IGNIDX) local++;
    int pos = i & (N_TOK / 4 - 1);        // chunk = 1024
    int te;
    if (pos < N_TOK / 4 - 1)      te = targ[i + 1];
    else if (i == N_TOK - 1)      te = IGNIDX;
    else                          te = targ[i + 2];
    ign[i] = (te == IGNIDX) ? 1 : 0;
    te = te < 0 ? 0 : (te > NCLS - 1 ? NCLS - 1 : te);
    teff[i] = te;
  }
#pragma unroll
  for (int d = 1; d < 64; d <<= 1) local += __shfl_xor(local, d);
  if ((threadIdx.x & 63) == 0) cnt[threadIdx.x >> 6] = local;
  __syncthreads();
  if (threadIdx.x == 0) {
    int t = 0;
    for (int i = 0; i < 16; i++) t += cnt[i];
    divisor[0] = (float)t;
  }
}

// Stage one half-tile (128 rows x 64 cols bf16) global -> LDS, linear LDS dest,
// inverse-swizzled global source (granule slot s at row r holds logical c4 = s ^ (r&7)).
// src must point at (row0, k0) of a row-major [.,DIM] bf16 matrix.
__device__ __forceinline__ void stage_half(const u16* src, u16* dstBase, int w, int l) {
  const int lr = l >> 3;                 // row within 8-row stripe
  const int lc = (l & 7) ^ lr;           // logical col-granule this lane must fetch
#pragma unroll
  for (int i = 0; i < 2; i++) {
    const int row = i * 64 + w * 8 + lr;
    __builtin_amdgcn_global_load_lds(
        (__attribute__((address_space(1))) void*)(src + (size_t)row * DIM + lc * 8),
        (__attribute__((address_space(3))) void*)(dstBase + (size_t)(i * 64 + w * 8) * BK),
        16, 0, 0);
  }
}

// ---- fused 256x256 8-phase GEMM + online per-tile sum(exp) partials ----
__launch_bounds__(512, 2)
__global__ void gemm_lse(const u16* __restrict__ Xb, const u16* __restrict__ Wb,
                         const int* __restrict__ teff, float* __restrict__ gt,
                         float* __restrict__ partial) {
  __shared__ u16 Abuf[2][BM][BK];   // 64 KiB
  __shared__ u16 Bbuf[2][BN][BK];   // 64 KiB

  const int tid = threadIdx.x;
  const int w = tid >> 6, l = tid & 63;
  const int wm = w >> 2, wn = w & 3;          // 2 x 4 wave grid
  const int hi = l >> 4, lo = l & 15;

  // XCD-chunked bijective swizzle (2000 % 8 == 0)
  const int bid = blockIdx.x;
  const int wg = (bid & 7) * (NTM * NTN / 8) + (bid >> 3);
  const int bx = wg & (NTM - 1), by = wg >> 4;      // row-tile, col-tile
  const int rowBase = bx * BM, colBase = by * BN;

  const u16* Asrc = Xb + (size_t)rowBase * DIM;
  const u16* Bsrc = Wb + (size_t)colBase * DIM;

  f32x4 acc[8][4] = {};

  // prologue: stage K-tile 0 into buf 0, full drain once
  stage_half(Asrc, &Abuf[0][0][0], w, l);
  stage_half(Asrc + (size_t)128 * DIM, &Abuf[0][128][0], w, l);
  stage_half(Bsrc, &Bbuf[0][0][0], w, l);
  stage_half(Bsrc + (size_t)128 * DIM, &Bbuf[0][128][0], w, l);
  asm volatile("s_waitcnt vmcnt(0)" ::: "memory");
  __builtin_amdgcn_s_barrier();

  for (int t = 0; t < KT; t++) {
    const int cur = t & 1, nxt = cur ^ 1;
    const u16(*Ac)[BK] = Abuf[cur];
    const u16(*Bc)[BK] = Bbuf[cur];
    const int kNext = (t + 1) * BK;

#pragma unroll
    for (int p = 0; p < 4; p++) {
      const int mB = (p >> 1) * 4, nB = (p & 1) * 2;

      // ds-read this phase's register subtile (12 x ds_read_b128, swizzled)
      bf16x8 af[4][2], bfv[2][2];
#pragma unroll
      for (int mm = 0; mm < 4; mm++) {
        const int r = wm * 128 + (mB + mm) * 16 + lo;
#pragma unroll
        for (int kk = 0; kk < 2; kk++)
          af[mm][kk] = *(const bf16x8*)&Ac[r][((((kk << 2) | hi)) ^ (l & 7)) * 8];
      }
#pragma unroll
      for (int nn = 0; nn < 2; nn++) {
        const int r = wn * 64 + (nB + nn) * 16 + lo;
#pragma unroll
        for (int kk = 0; kk < 2; kk++)
          bfv[nn][kk] = *(const bf16x8*)&Bc[r][((((kk << 2) | hi)) ^ (l & 7)) * 8];
      }

      // prefetch one half-tile of K-tile t+1 (2 x global_load_lds, stays in flight)
      if (t < KT - 1) {
        if (p == 0)      stage_half(Asrc + kNext, &Abuf[nxt][0][0], w, l);
        else if (p == 1) stage_half(Asrc + (size_t)128 * DIM + kNext, &Abuf[nxt][128][0], w, l);
        else if (p == 2) stage_half(Bsrc + kNext, &Bbuf[nxt][0][0], w, l);
        else             stage_half(Bsrc + (size_t)128 * DIM + kNext, &Bbuf[nxt][128][0], w, l);
      }

      asm volatile("" ::: "memory");
      __builtin_amdgcn_s_barrier();

      __builtin_amdgcn_s_setprio(1);
#pragma unroll
      for (int mm = 0; mm < 4; mm++)
#pragma unroll
        for (int nn = 0; nn < 2; nn++)
#pragma unroll
          for (int kk = 0; kk < 2; kk++)
            acc[mB + mm][nB + nn] = __builtin_amdgcn_mfma_f32_16x16x32_bf16(
                af[mm][kk], bfv[nn][kk], acc[mB + mm][nB + nn], 0, 0, 0);
      __builtin_amdgcn_s_setprio(0);

      // boundary: wait prefetched K-tile (only here, never mid-tile)
      if (p == 3 && t < KT - 1) asm volatile("s_waitcnt vmcnt(0)" ::: "memory");
      asm volatile("" ::: "memory");
      __builtin_amdgcn_s_barrier();
    }
  }

  // ---- epilogue: per-row sum(exp) over this 256-col tile + gt extraction ----
  float* red = (float*)&Abuf[0][0][0];   // 4 KiB alias (last tile read buf 1)
#pragma unroll
  for (int m = 0; m < 8; m++) {
#pragma unroll
    for (int j = 0; j < 4; j++) {
      const int rloc = wm * 128 + m * 16 + hi * 4 + j;
      const int gr = rowBase + rloc;
      const int te = teff[gr];
      float s = 0.f;
#pragma unroll
      for (int n = 0; n < 4; n++) {
        float v = acc[m][n][j];
        const int gc = colBase + wn * 64 + n * 16 + lo;
        if (te == gc) gt[gr] = v;
        s += __expf(v);
      }
#pragma unroll
      for (int d = 1; d < 16; d <<= 1) s += __shfl_xor(s, d);
      if (lo == 0) red[wn * 256 + rloc] = s;
    }
  }
  __syncthreads();
  if (tid < 256) {
    float S = red[tid] + red[256 + tid] + red[512 + tid] + red[768 + tid];
    partial[(size_t)(rowBase + tid) * NTN + by] = S;
  }
}

// ---- combine 125 tile partials per row -> per-token loss ----
__global__ void reduce_lse(const float* __restrict__ partial, const float* __restrict__ gt,
                           const int* __restrict__ ign, const float* __restrict__ divisor,
                           float* __restrict__ pertok) {
  int r = blockIdx.x * 4 + (threadIdx.x >> 6);
  int l = threadIdx.x & 63;
  float S = 0.f;
  for (int p = l; p < NTN; p += 64) S += partial[(size_t)r * NTN + p];
#pragma unroll
  for (int d = 1; d < 64; d <<= 1) S += __shfl_xor(S, d);
  if (l == 0) {
    float lse = __logf(S);
    pertok[r] = ign[r] ? 0.f : (lse - gt[r]) / divisor[0];
  }
}

// ---- deterministic final sum ----
__global__ void final_sum(const float* __restrict__ pertok, float* __restrict__ out) {
  __shared__ float red[16];
  float s = 0.f;
  for (int i = threadIdx.x; i < N_TOK; i += 1024) s += pertok[i];
#pragma unroll
  for (int d = 1; d < 64; d <<= 1) s += __shfl_xor(s, d);
  if ((threadIdx.x & 63) == 0) red[threadIdx.x >> 6] = s;
  __syncthreads();
  if (threadIdx.x == 0) {
    float t = 0.f;
    for (int i = 0; i < 16; i++) t += red[i];
    out[0] = t;
  }
}

extern "C" void kernel_launch(void* const* d_in, const int* in_sizes, int n_in,
                              void* d_out, int out_size, void* d_ws, size_t ws_size,
                              hipStream_t stream) {
  const float* x = (const float*)d_in[0];       // [4096,1024] f32
  const float* w = (const float*)d_in[1];       // [32000,1024] f32
  const int* targ = (const int*)d_in[2];        // [4096] int
  float* out = (float*)d_out;

  char* ws = (char*)d_ws;
  u16*   Xb      = (u16*)(ws);                     // 8,388,608 B
  u16*   Wb      = (u16*)(ws + 8388608);           // 65,536,000 B
  float* partial = (float*)(ws + 73924608);        // 2,048,000 B
  float* gt      = (float*)(ws + 75972608);        // 16,384 B
  int*   teff    = (int*)(ws + 75988992);          // 16,384 B
  int*   ign     = (int*)(ws + 76005376);          // 16,384 B
  float* divisor = (float*)(ws + 76021760);        // 256 B
  float* pertok  = (float*)(ws + 76022016);        // 16,384 B

  {
    int n8 = N_TOK * DIM / 8;
    cvt_bf16<<<(n8 + 255) / 256, 256, 0, stream>>>((const float4*)x, (u16x8*)Xb, n8);
  }
  {
    int n8 = NCLS * DIM / 8;
    cvt_bf16<<<(n8 + 255) / 256, 256, 0, stream>>>((const float4*)w, (u16x8*)Wb, n8);
  }
  prep_targ<<<1, 1024, 0, stream>>>(targ, teff, ign, divisor);

  gemm_lse<<<NTM * NTN, 512, 0, stream>>>(Xb, Wb, teff, gt, partial);  // 2000 blocks

  reduce_lse<<<N_TOK / 4, 256, 0, stream>>>(partial, gt, ign, divisor, pertok);
  final_sum<<<1, 1024, 0, stream>>>(pertok, out);
}